// Round 1
// 632.827 us; speedup vs baseline: 1.2602x; 1.2602x over previous
//
#include <hip/hip_runtime.h>
#include <math.h>

// Problem constants (B,R,L,H)=(2,64,512,1024), NH=8, HD=64, AH=512
typedef __attribute__((ext_vector_type(8))) short short8;   // 8 bf16 (4 VGPR)
typedef __attribute__((ext_vector_type(4))) float floatx4;  // MFMA acc

__device__ __forceinline__ unsigned int pack2_trunc(float a, float b) {
  // two f32 -> packed bf16 (truncate) : 3 VALU
  return (__float_as_uint(a) >> 16) | (__float_as_uint(b) & 0xffff0000u);
}
__device__ __forceinline__ unsigned short f2bf_rne(float x) {
  unsigned int u = __float_as_uint(x);
  u += 0x7fff + ((u >> 16) & 1);
  return (unsigned short)(u >> 16);
}
__device__ __forceinline__ float bflo(unsigned int u) { return __uint_as_float(u << 16); }
__device__ __forceinline__ float bfhi(unsigned int u) { return __uint_as_float(u & 0xffff0000u); }

// ---------------------------------------------------------------------------
// Kernel 0: one-time Wv fp32 -> bf16 cast (trunc, matching the old staging
// path bit-exactly).  512*1024 elems.  grid=(256), block 256, 8 elems/thread.
// ---------------------------------------------------------------------------
__global__ __launch_bounds__(256) void wcast_kernel(
    const float* __restrict__ W, unsigned short* __restrict__ Wb)
{
  size_t i = (size_t)blockIdx.x * 256 + threadIdx.x;
  const float4* p = (const float4*)(W + i * 8);
  float4 a0 = p[0], a1 = p[1];
  uint4 w;
  w.x = pack2_trunc(a0.x, a0.y); w.y = pack2_trunc(a0.z, a0.w);
  w.z = pack2_trunc(a1.x, a1.y); w.w = pack2_trunc(a1.z, a1.w);
  *(uint4*)&Wb[i * 8] = w;
}

// ---------------------------------------------------------------------------
// Kernel 1: Q/K projection.  C[m=(b,l)][n=ah] = row0 @ W^T + bias, bf16 out
// row-major (M=1024, N=512).  grid=(4, 8, 2) z: 0=Q 1=K.  128x128 tile, BK=64.
// ---------------------------------------------------------------------------
__global__ __launch_bounds__(256, 2) void qk_proj_kernel(
    const float* __restrict__ hid,
    const float* __restrict__ Wq, const float* __restrict__ bq,
    const float* __restrict__ Wk, const float* __restrict__ bk,
    unsigned short* __restrict__ Qr, unsigned short* __restrict__ Kr)
{
  const float* W = blockIdx.z ? Wk : Wq;
  const float* bias = blockIdx.z ? bk : bq;
  unsigned short* out = blockIdx.z ? Kr : Qr;

  __shared__ unsigned short As[128][72];
  __shared__ unsigned short Bs[128][72];
  const int tid = threadIdx.x;
  const int m0 = blockIdx.y * 128;      // m = b*512 + l
  const int n0 = blockIdx.x * 128;
  const int bidx = m0 >> 9;
  const int l0 = m0 & 511;
  const float* Abase = hid + ((size_t)bidx * 32768 + l0) * 1024;  // hidden[b,0,l,:]
  const float* Bbase = W + (size_t)n0 * 1024;

  const int srow = tid >> 1;
  const int shalf = (tid & 1) * 32;
  const int lane = tid & 63;
  const int wave = tid >> 6;
  const int wm = (wave >> 1) * 64, wn = (wave & 1) * 64;
  const int mr = lane & 15, kq = lane >> 4;

  floatx4 acc[4][4];
#pragma unroll
  for (int i = 0; i < 4; ++i)
#pragma unroll
    for (int j = 0; j < 4; ++j) acc[i][j] = (floatx4){0.f, 0.f, 0.f, 0.f};

  for (int k0 = 0; k0 < 1024; k0 += 64) {
    const float4* ap = (const float4*)(Abase + (size_t)srow * 1024 + k0 + shalf);
    const float4* bp = (const float4*)(Bbase + (size_t)srow * 1024 + k0 + shalf);
#pragma unroll
    for (int j = 0; j < 4; ++j) {
      float4 a0 = ap[2 * j], a1 = ap[2 * j + 1];
      float4 b0 = bp[2 * j], b1 = bp[2 * j + 1];
      uint4 wa, wb;
      wa.x = pack2_trunc(a0.x, a0.y); wa.y = pack2_trunc(a0.z, a0.w);
      wa.z = pack2_trunc(a1.x, a1.y); wa.w = pack2_trunc(a1.z, a1.w);
      wb.x = pack2_trunc(b0.x, b0.y); wb.y = pack2_trunc(b0.z, b0.w);
      wb.z = pack2_trunc(b1.x, b1.y); wb.w = pack2_trunc(b1.z, b1.w);
      *(uint4*)&As[srow][shalf + j * 8] = wa;
      *(uint4*)&Bs[srow][shalf + j * 8] = wb;
    }
    __syncthreads();
#pragma unroll
    for (int ks = 0; ks < 2; ++ks) {
      short8 af[4], bfr[4];
#pragma unroll
      for (int i = 0; i < 4; ++i)
        af[i] = *(const short8*)&As[wm + i * 16 + mr][ks * 32 + kq * 8];
#pragma unroll
      for (int i = 0; i < 4; ++i)
        bfr[i] = *(const short8*)&Bs[wn + i * 16 + mr][ks * 32 + kq * 8];
#pragma unroll
      for (int i = 0; i < 4; ++i)
#pragma unroll
        for (int j = 0; j < 4; ++j)
          acc[i][j] = __builtin_amdgcn_mfma_f32_16x16x32_bf16(af[i], bfr[j], acc[i][j], 0, 0, 0);
    }
    __syncthreads();
  }

#pragma unroll
  for (int j = 0; j < 4; ++j) {
    int gn = n0 + wn + j * 16 + mr;
    float bb = bias[gn];
#pragma unroll
    for (int i = 0; i < 4; ++i) {
      int gm = m0 + wm + i * 16 + kq * 4;
      floatx4 a = acc[i][j];
#pragma unroll
      for (int rg = 0; rg < 4; ++rg)
        out[(size_t)(gm + rg) * 512 + gn] = f2bf_rne(a[rg] + bb);
    }
  }
}

// ---------------------------------------------------------------------------
// Kernel 2: rope(Q) @ rope(K)^T / 8 -> softmax -> probs bf16 [b][n][q][k].
// grid=(64 qchunks of 8, 16 bn), block 256.  K staged rope'd as packed bf16
// pairs in LDS (pad 34 breaks row-stride bank aliasing).
// ---------------------------------------------------------------------------
__global__ __launch_bounds__(256, 2) void scores_softmax_kernel(
    const unsigned short* __restrict__ Qr,
    const unsigned short* __restrict__ Kr,
    const float* __restrict__ sinu,
    unsigned short* __restrict__ probs)
{
  __shared__ unsigned int KsL[512][34];
  __shared__ float Qs[8][64];
  const int tid = threadIdx.x;
  const int bn = blockIdx.y;
  const int b = bn >> 3, h = bn & 7;
  const int q0 = blockIdx.x * 8;

  for (int it = tid; it < 4096; it += 256) {
    int k = it >> 3, c = it & 7;
    uint4 v = *(const uint4*)(Kr + ((size_t)b * 512 + k) * 512 + h * 64 + c * 8);
    unsigned int uu[4] = {v.x, v.y, v.z, v.w};
#pragma unroll
    for (int p = 0; p < 4; ++p) {
      int i = c * 4 + p;  // pair index 0..31, d = 2i,2i+1
      float x0 = bflo(uu[p]), x1 = bfhi(uu[p]);
      float sn = sinu[k * 64 + i], cs = sinu[k * 64 + 32 + i];
      KsL[k][i] = pack2_trunc(x0 * cs - x1 * sn, x1 * cs + x0 * sn);
    }
  }
  if (tid < 64) {
    int q = tid >> 3, c = tid & 7;
    int gq = q0 + q;
    uint4 v = *(const uint4*)(Qr + ((size_t)b * 512 + gq) * 512 + h * 64 + c * 8);
    unsigned int uu[4] = {v.x, v.y, v.z, v.w};
#pragma unroll
    for (int p = 0; p < 4; ++p) {
      int i = c * 4 + p;
      float x0 = bflo(uu[p]), x1 = bfhi(uu[p]);
      float sn = sinu[gq * 64 + i], cs = sinu[gq * 64 + 32 + i];
      Qs[q][2 * i] = (x0 * cs - x1 * sn) * 0.125f;       // fold 1/sqrt(HD)
      Qs[q][2 * i + 1] = (x1 * cs + x0 * sn) * 0.125f;
    }
  }
  __syncthreads();

  const int q = tid >> 5, kg = tid & 31;  // 32 lanes per q-row (same half-wave)
  float qreg[64];
#pragma unroll
  for (int d = 0; d < 64; ++d) qreg[d] = Qs[q][d];

  float s[16];
#pragma unroll
  for (int j = 0; j < 16; ++j) {
    int kk = kg + 32 * j;
    float a = 0.f;
#pragma unroll
    for (int c = 0; c < 16; ++c) {
      uint2 u = *(const uint2*)&KsL[kk][2 * c];
      a += qreg[4 * c + 0] * bflo(u.x);
      a += qreg[4 * c + 1] * bfhi(u.x);
      a += qreg[4 * c + 2] * bflo(u.y);
      a += qreg[4 * c + 3] * bfhi(u.y);
    }
    s[j] = a;
  }
  float mx = s[0];
#pragma unroll
  for (int j = 1; j < 16; ++j) mx = fmaxf(mx, s[j]);
#pragma unroll
  for (int off = 1; off < 32; off <<= 1) mx = fmaxf(mx, __shfl_xor(mx, off));
  float sum = 0.f;
#pragma unroll
  for (int j = 0; j < 16; ++j) { s[j] = __expf(s[j] - mx); sum += s[j]; }
#pragma unroll
  for (int off = 1; off < 32; off <<= 1) sum += __shfl_xor(sum, off);
  float inv = 1.0f / sum;
  unsigned short* prow = probs + ((size_t)bn * 512 + (q0 + q)) * 512;
#pragma unroll
  for (int j = 0; j < 16; ++j) prow[kg + 32 * j] = f2bf_rne(s[j] * inv);
}

// ---------------------------------------------------------------------------
// Kernel 3: V projection, full-N tile.  M=65536 (m=(b,r,l)), N=512 (ah).
// Each block: 128 m-rows x ALL 512 n-cols -> hid fetched from HBM exactly
// once (was 4x).  512 threads = 8 waves (2m x 4n), wave tile 64x128,
// acc[4][8].  B = pre-cast bf16 Wv (L2-resident, re-read per block).
// LDS = 18K (A) + 72K (B) = 90K -> 1 block/CU, 2 waves/SIMD; traffic-bound
// so latency hiding comes from 12 in-flight 16B loads/thread per k-step.
// Output scattered to V_T[b][n][r*64+d][l] bf16 (B^T layout for ctx GEMM).
// grid=(512).
// ---------------------------------------------------------------------------
__global__ __launch_bounds__(512, 1) void vproj_kernel(
    const float* __restrict__ hid, const unsigned short* __restrict__ Wvb,
    const float* __restrict__ bv, unsigned short* __restrict__ VT)
{
  __shared__ unsigned short As[128][72];
  __shared__ unsigned short Bs[512][72];
  const int tid = threadIdx.x;
  const int m0 = blockIdx.x * 128;
  const float* Abase = hid + (size_t)m0 * 1024;

  const int lane = tid & 63;
  const int wave = tid >> 6;
  const int wm = (wave >> 2) * 64, wn = (wave & 3) * 128;
  const int mr = lane & 15, kq = lane >> 4;

  // A staging: row = tid>>2 (0..127), seg = tid&3 (16 floats = 64B each)
  const int arow = tid >> 2, aseg = tid & 3;
  // B staging: row = (tid>>3) + j*64, chunk = tid&7 (8 bf16 = 16B)
  const int brow = tid >> 3, bchunk = tid & 7;

  floatx4 acc[4][8];
#pragma unroll
  for (int i = 0; i < 4; ++i)
#pragma unroll
    for (int j = 0; j < 8; ++j) acc[i][j] = (floatx4){0.f, 0.f, 0.f, 0.f};

  for (int k0 = 0; k0 < 1024; k0 += 64) {
    // A: 16 fp32 -> 16 bf16 per thread
    const float4* ap = (const float4*)(Abase + (size_t)arow * 1024 + k0 + aseg * 16);
    float4 a0 = ap[0], a1 = ap[1], a2 = ap[2], a3 = ap[3];
    uint4 w0, w1;
    w0.x = pack2_trunc(a0.x, a0.y); w0.y = pack2_trunc(a0.z, a0.w);
    w0.z = pack2_trunc(a1.x, a1.y); w0.w = pack2_trunc(a1.z, a1.w);
    w1.x = pack2_trunc(a2.x, a2.y); w1.y = pack2_trunc(a2.z, a2.w);
    w1.z = pack2_trunc(a3.x, a3.y); w1.w = pack2_trunc(a3.z, a3.w);
    *(uint4*)&As[arow][aseg * 16] = w0;
    *(uint4*)&As[arow][aseg * 16 + 8] = w1;
    // B: 512 rows x 64 k of bf16 Wv, 8 x 16B per thread (L2-resident)
#pragma unroll
    for (int j = 0; j < 8; ++j) {
      int r = brow + j * 64;
      uint4 v = *(const uint4*)(Wvb + (size_t)r * 1024 + k0 + bchunk * 8);
      *(uint4*)&Bs[r][bchunk * 8] = v;
    }
    __syncthreads();
#pragma unroll
    for (int ks = 0; ks < 2; ++ks) {
      short8 af[4], bfr[8];
#pragma unroll
      for (int i = 0; i < 4; ++i)
        af[i] = *(const short8*)&As[wm + i * 16 + mr][ks * 32 + kq * 8];
#pragma unroll
      for (int j = 0; j < 8; ++j)
        bfr[j] = *(const short8*)&Bs[wn + j * 16 + mr][ks * 32 + kq * 8];
#pragma unroll
      for (int i = 0; i < 4; ++i)
#pragma unroll
        for (int j = 0; j < 8; ++j)
          acc[i][j] = __builtin_amdgcn_mfma_f32_16x16x32_bf16(af[i], bfr[j], acc[i][j], 0, 0, 0);
    }
    __syncthreads();
  }

  // m-tile (128 rows) sits inside one (b,r): 512 % 128 == 0
  const int bidx = m0 >> 15;
  const int rr = (m0 >> 9) & 63;
  const int l0 = m0 & 511;
#pragma unroll
  for (int j = 0; j < 8; ++j) {
    int gn = wn + j * 16 + mr;
    int hh = gn >> 6, dd = gn & 63;
    float bb = bv[gn];
    size_t colbase = ((size_t)(bidx * 8 + hh) * 4096 + rr * 64 + dd) * 512;
#pragma unroll
    for (int i = 0; i < 4; ++i) {
      int gl = l0 + wm + i * 16 + kq * 4;  // 4 consecutive l per lane
      floatx4 a = acc[i][j];
      uint2 pk;
      pk.x = (unsigned int)f2bf_rne(a[0] + bb) | ((unsigned int)f2bf_rne(a[1] + bb) << 16);
      pk.y = (unsigned int)f2bf_rne(a[2] + bb) | ((unsigned int)f2bf_rne(a[3] + bb) << 16);
      *(uint2*)&VT[colbase + gl] = pk;
    }
  }
}

// ---------------------------------------------------------------------------
// Kernel 4: ctx.  Per z=(b,n): C[q][r*64+d] = probs[b,n] (512x512) @
// V_T[b,n] (4096x512 B^T).  fp32 out scattered to out[b][r][q][n*64+d].
// grid=(32, 4, 16).
// ---------------------------------------------------------------------------
__global__ __launch_bounds__(256, 2) void ctx_kernel(
    const unsigned short* __restrict__ probs,
    const unsigned short* __restrict__ VT,
    float* __restrict__ out)
{
  __shared__ unsigned short As[128][72];
  __shared__ unsigned short Bs[128][72];
  const int tid = threadIdx.x;
  const int n0 = blockIdx.x * 128;
  const int m0 = blockIdx.y * 128;
  const int z = blockIdx.z;  // b*8+h
  const unsigned short* Ab = probs + (size_t)z * 512 * 512;
  const unsigned short* Bb = VT + (size_t)z * 4096 * 512;

  const int srow = tid >> 1;
  const int shalf = (tid & 1) * 32;
  const int lane = tid & 63;
  const int wave = tid >> 6;
  const int wm = (wave >> 1) * 64, wn = (wave & 1) * 64;
  const int mr = lane & 15, kq = lane >> 4;

  floatx4 acc[4][4];
#pragma unroll
  for (int i = 0; i < 4; ++i)
#pragma unroll
    for (int j = 0; j < 4; ++j) acc[i][j] = (floatx4){0.f, 0.f, 0.f, 0.f};

  for (int k0 = 0; k0 < 512; k0 += 64) {
    const uint4* ap = (const uint4*)(Ab + (size_t)(m0 + srow) * 512 + k0 + shalf);
    const uint4* bp = (const uint4*)(Bb + (size_t)(n0 + srow) * 512 + k0 + shalf);
#pragma unroll
    for (int j = 0; j < 4; ++j) {
      *(uint4*)&As[srow][shalf + j * 8] = ap[j];
      *(uint4*)&Bs[srow][shalf + j * 8] = bp[j];
    }
    __syncthreads();
#pragma unroll
    for (int ks = 0; ks < 2; ++ks) {
      short8 af[4], bfr[4];
#pragma unroll
      for (int i = 0; i < 4; ++i)
        af[i] = *(const short8*)&As[wm + i * 16 + mr][ks * 32 + kq * 8];
#pragma unroll
      for (int i = 0; i < 4; ++i)
        bfr[i] = *(const short8*)&Bs[wn + i * 16 + mr][ks * 32 + kq * 8];
#pragma unroll
      for (int i = 0; i < 4; ++i)
#pragma unroll
        for (int j = 0; j < 4; ++j)
          acc[i][j] = __builtin_amdgcn_mfma_f32_16x16x32_bf16(af[i], bfr[j], acc[i][j], 0, 0, 0);
    }
    __syncthreads();
  }

  const int bz = z >> 3, hh = z & 7;
#pragma unroll
  for (int j = 0; j < 4; ++j) {
    int gn = n0 + wn + j * 16 + mr;  // r*64+d
    int rr = gn >> 6, dd = gn & 63;
    size_t colbase = (size_t)(bz * 64 + rr) * 262144 + hh * 64 + dd;
#pragma unroll
    for (int i = 0; i < 4; ++i) {
      int gq = m0 + wm + i * 16 + kq * 4;
      floatx4 a = acc[i][j];
#pragma unroll
      for (int rg = 0; rg < 4; ++rg)
        out[colbase + (size_t)(gq + rg) * 512] = a[rg];
    }
  }
}

// ---------------------------------------------------------------------------
extern "C" void kernel_launch(void* const* d_in, const int* in_sizes, int n_in,
                              void* d_out, int out_size, void* d_ws, size_t ws_size,
                              hipStream_t stream) {
  const float* hid  = (const float*)d_in[0];
  const float* sinu = (const float*)d_in[1];
  const float* Wq = (const float*)d_in[2];
  const float* bq = (const float*)d_in[3];
  const float* Wk = (const float*)d_in[4];
  const float* bk = (const float*)d_in[5];
  const float* Wv = (const float*)d_in[6];
  const float* bv = (const float*)d_in[7];
  float* out = (float*)d_out;

  // workspace layout (needs 80 MB):
  //  [0,1MB)   Qr  bf16 [b][l][ah]
  //  [1,2MB)   Kr  bf16 [b][l][ah]
  //  [2,10MB)  probs bf16 [b][n][q][k]
  //  [10,11MB) Wvb bf16 [ah][h]  (pre-cast Wv)
  //  [16,80MB) V_T bf16 [b][n][r*64+d][l]
  char* ws = (char*)d_ws;
  unsigned short* Qr = (unsigned short*)(ws);
  unsigned short* Kr = (unsigned short*)(ws + (1u << 20));
  unsigned short* probs = (unsigned short*)(ws + (2u << 20));
  unsigned short* Wvb = (unsigned short*)(ws + (10u << 20));
  unsigned short* VT = (unsigned short*)(ws + (16u << 20));

  wcast_kernel<<<dim3(256), 256, 0, stream>>>(Wv, Wvb);
  qk_proj_kernel<<<dim3(4, 8, 2), 256, 0, stream>>>(hid, Wq, bq, Wk, bk, Qr, Kr);
  scores_softmax_kernel<<<dim3(64, 16), 256, 0, stream>>>(Qr, Kr, sinu, probs);
  vproj_kernel<<<dim3(512), 512, 0, stream>>>(hid, Wvb, bv, VT);
  ctx_kernel<<<dim3(32, 4, 16), 256, 0, stream>>>(probs, VT, out);
}